// Round 4
// baseline (1434.641 us; speedup 1.0000x reference)
//
#include <hip/hip_runtime.h>

#define K_DIM 32

__device__ __forceinline__ float tanh_fast(float x) {
    // tanh(x) = 1 - 2/(e^{2x}+1); exact at saturation, ~1e-7 abs error
    float e = __expf(2.0f * x);
    return 1.0f - 2.0f / (e + 1.0f);
}

// ---------------- CSR build ----------------

__global__ void k_hist(const int* __restrict__ dst, int* __restrict__ cnt, int n) {
    for (int e = blockIdx.x * blockDim.x + threadIdx.x; e < n; e += gridDim.x * blockDim.x)
        atomicAdd(&cnt[dst[e]], 1);
}

__global__ void k_scan_part(const int* __restrict__ cnt, int* __restrict__ part) {
    __shared__ int sm[256];
    int t = threadIdx.x;
    int g = blockIdx.x * 1024 + t * 4;
    const int4 v = *(const int4*)(cnt + g);
    sm[t] = v.x + v.y + v.z + v.w;
    __syncthreads();
    #pragma unroll
    for (int d = 128; d > 0; d >>= 1) {
        if (t < d) sm[t] += sm[t + d];
        __syncthreads();
    }
    if (t == 0) part[blockIdx.x] = sm[0];
}

__global__ void k_scan_top(int* __restrict__ part, int nblk,
                           int* __restrict__ off, int n, int total) {
    __shared__ int sm[128];
    int t = threadIdx.x;
    sm[t] = (t < nblk) ? part[t] : 0;
    __syncthreads();
    #pragma unroll
    for (int d = 1; d < 128; d <<= 1) {
        int v = (t >= d) ? sm[t - d] : 0;
        __syncthreads();
        sm[t] += v;
        __syncthreads();
    }
    if (t < nblk) part[t] = sm[t];
    if (t == 0) off[n] = total;
}

__global__ void k_scan_apply(const int* __restrict__ cnt, const int* __restrict__ part,
                             int* __restrict__ off, int* __restrict__ cur, int n) {
    __shared__ int sm[256];
    int t = threadIdx.x;
    int g = blockIdx.x * 1024 + t * 4;
    const int4 v = *(const int4*)(cnt + g);
    int s0 = v.x, s1 = s0 + v.y, s2 = s1 + v.z, s3 = s2 + v.w;
    sm[t] = s3;
    __syncthreads();
    #pragma unroll
    for (int d = 1; d < 256; d <<= 1) {
        int tv = (t >= d) ? sm[t - d] : 0;
        __syncthreads();
        sm[t] += tv;
        __syncthreads();
    }
    int carry = blockIdx.x ? part[blockIdx.x - 1] : 0;
    int excl = (t ? sm[t - 1] : 0) + carry;
    if (g + 3 < n) {
        int4 o = make_int4(excl, excl + s0, excl + s1, excl + s2);
        *(int4*)(off + g) = o;
        *(int4*)(cur + g) = o;
    } else {
        int pre[4] = {0, s0, s1, s2};
        #pragma unroll
        for (int j = 0; j < 4; ++j)
            if (g + j < n) { off[g + j] = excl + pre[j]; cur[g + j] = excl + pre[j]; }
    }
}

// scatter restricted to dst in [lo,hi): write window ~3.2MB -> L2-resident
__global__ void k_scatter_slice(const int* __restrict__ src, const int* __restrict__ dst,
                                const float* __restrict__ ea, int* __restrict__ cur,
                                uint2* __restrict__ packed, int n, int lo, int hi) {
    for (int e = blockIdx.x * blockDim.x + threadIdx.x; e < n; e += gridDim.x * blockDim.x) {
        int d = dst[e];
        if (d >= lo && d < hi) {
            int pos = atomicAdd(&cur[d], 1);
            packed[pos] = make_uint2((unsigned)src[e], __float_as_uint(ea[e]));
        }
    }
}

// ---------------- per-layer kernels ----------------

__global__ void k_node_gemm5(const float* __restrict__ h, const float* __restrict__ p,
                             const float* __restrict__ Wx, const float* __restrict__ Wp,
                             float* __restrict__ M, int n_nodes) {
    __shared__ float sWx[5 * 32];
    __shared__ float sWp[96];
    for (int i = threadIdx.x; i < 5 * 32; i += blockDim.x) sWx[i] = Wx[i];
    if (threadIdx.x < 96) sWp[threadIdx.x] = Wp[threadIdx.x];
    __syncthreads();
    const int k = threadIdx.x & 31;
    int n = blockIdx.x * (blockDim.x >> 5) + (threadIdx.x >> 5);
    if (n >= n_nodes) return;
    float hv = (k < 5) ? h[n * 5 + k] : 0.0f;
    float pv = (k < 3) ? p[n * 3 + k] : 0.0f;
    float acc = 0.0f;
    #pragma unroll
    for (int j = 0; j < 5; ++j) acc = fmaf(__shfl(hv, j, 32), sWx[j * 32 + k], acc);
    #pragma unroll
    for (int j = 0; j < 3; ++j) acc = fmaf(__shfl(pv, j, 32), sWp[j * 32 + k], acc);
    M[n * 32 + k] = acc;
}

// one wave64 per node: lanes = k(0..31) x half(0..1); 2 edges per inner iter
__global__ void k_edge_msg(const float* __restrict__ M, const float* __restrict__ p,
                           const int* __restrict__ off, const uint2* __restrict__ packed,
                           const float* __restrict__ Wp, const float* __restrict__ We,
                           const float* __restrict__ b,
                           float* __restrict__ sim, int n_nodes) {
    __shared__ uint2 stage[4][64];
    const int wid = threadIdx.x >> 6;
    const int lane = threadIdx.x & 63;
    const int k = lane & 31;
    const int half = lane >> 5;
    int n = blockIdx.x * 4 + wid;
    if (n >= n_nodes) return;

    float pn = (k < 3) ? p[n * 3 + k] : 0.0f;
    float cnst = b[k] - (__shfl(pn, 0, 32) * Wp[k] + __shfl(pn, 1, 32) * Wp[32 + k]
                         + __shfl(pn, 2, 32) * Wp[64 + k]);
    float we = We[k];
    float acc = 0.0f;

    int e0 = off[n], e1 = off[n + 1];
    int nedge = e1 - e0;
    int nfull = nedge & ~63;
    int end_full = e0 + nfull;

    if (nfull) {
        uint2 pk = packed[e0 + lane];                       // prefetched chunk
        for (int base = e0; base < end_full; base += 64) {
            stage[wid][lane] = pk;
            int nxt = base + 64;
            if (nxt < end_full) pk = packed[nxt + lane];    // prefetch next
            #pragma unroll 16
            for (int j = 0; j < 32; ++j) {
                uint2 epk = stage[wid][2 * j + half];
                float pre = fmaf(__uint_as_float(epk.y), we, cnst)
                            + M[(int)epk.x * 32 + k];
                acc += tanh_fast(pre);
            }
        }
    }
    int rem = e1 - end_full;                                // 0..63
    if (rem) {
        if (lane < rem) stage[wid][lane] = packed[end_full + lane];
        int m = (rem + 1) >> 1;
        for (int j = 0; j < m; ++j) {
            int idx = 2 * j + half;
            if (idx < rem) {
                uint2 epk = stage[wid][idx];
                float pre = fmaf(__uint_as_float(epk.y), we, cnst)
                            + M[(int)epk.x * 32 + k];
                acc += tanh_fast(pre);
            }
        }
    }
    acc += __shfl_xor(acc, 32);                             // combine halves
    if (lane < 32) sim[n * 32 + k] = acc;
}

// h_next[n] = sum over in-edges of sim[src]; optionally fused next-layer GEMM
template <int FUSE>
__global__ void k_prop_gemm(const float* __restrict__ sim, const int* __restrict__ off,
                            const uint2* __restrict__ packed, const float* __restrict__ p,
                            const float* __restrict__ Wx, const float* __restrict__ Wp,
                            float* __restrict__ outM, int n_nodes) {
    __shared__ uint2 stage[4][64];
    __shared__ float sWx[1024];
    if (FUSE) {
        for (int i = threadIdx.x; i < 1024; i += blockDim.x) sWx[i] = Wx[i];
        __syncthreads();
    }
    const int wid = threadIdx.x >> 6;
    const int lane = threadIdx.x & 63;
    const int k = lane & 31;
    const int half = lane >> 5;
    int n = blockIdx.x * 4 + wid;
    if (n >= n_nodes) return;

    float acc = 0.0f;
    int e0 = off[n], e1 = off[n + 1];
    int nedge = e1 - e0;
    int nfull = nedge & ~63;
    int end_full = e0 + nfull;

    if (nfull) {
        uint2 pk = packed[e0 + lane];
        for (int base = e0; base < end_full; base += 64) {
            stage[wid][lane] = pk;
            int nxt = base + 64;
            if (nxt < end_full) pk = packed[nxt + lane];
            #pragma unroll 16
            for (int j = 0; j < 32; ++j) {
                uint2 epk = stage[wid][2 * j + half];
                acc += sim[(int)epk.x * 32 + k];
            }
        }
    }
    int rem = e1 - end_full;
    if (rem) {
        if (lane < rem) stage[wid][lane] = packed[end_full + lane];
        int m = (rem + 1) >> 1;
        for (int j = 0; j < m; ++j) {
            int idx = 2 * j + half;
            if (idx < rem) acc += sim[(int)stage[wid][idx].x * 32 + k];
        }
    }
    acc += __shfl_xor(acc, 32);                             // both halves hold total

    if (!FUSE) {
        if (lane < 32) outM[n * 32 + k] = acc;
        return;
    }
    float mm = 0.0f;
    #pragma unroll
    for (int j = 0; j < 32; ++j) mm = fmaf(__shfl(acc, j, 32), sWx[j * 32 + k], mm);
    float pv = (k < 3) ? p[n * 3 + k] : 0.0f;
    mm = fmaf(__shfl(pv, 0, 32), Wp[k], mm);
    mm = fmaf(__shfl(pv, 1, 32), Wp[32 + k], mm);
    mm = fmaf(__shfl(pv, 2, 32), Wp[64 + k], mm);
    if (lane < 32) outM[n * 32 + k] = mm;
}

// ---------------- pooling + head ----------------

__global__ void k_pool(const float* __restrict__ h, const int* __restrict__ batch,
                       const float* __restrict__ Wh, const float* __restrict__ bh,
                       float* __restrict__ out, int n_nodes, int n_graphs) {
    __shared__ int sLo, sHi;
    __shared__ float red[256];
    int g = blockIdx.x;
    if (threadIdx.x == 0) {
        int lo = 0, hi = n_nodes;
        while (lo < hi) { int m = (lo + hi) >> 1; if (batch[m] < g) lo = m + 1; else hi = m; }
        sLo = lo;
        lo = 0; hi = n_nodes; int g1 = g + 1;
        while (lo < hi) { int m = (lo + hi) >> 1; if (batch[m] < g1) lo = m + 1; else hi = m; }
        sHi = lo;
    }
    __syncthreads();
    int lo = sLo, hi = sHi;
    int k = threadIdx.x & 31, r = threadIdx.x >> 5;
    float acc = 0.0f;
    for (int n = lo + r; n < hi; n += 8) acc += h[n * 32 + k];
    red[threadIdx.x] = acc;
    __syncthreads();
    if (threadIdx.x < 32) {
        float s = 0.0f;
        #pragma unroll
        for (int r2 = 0; r2 < 8; ++r2) s += red[r2 * 32 + k];
        float c = (float)(hi - lo);
        float rep = s / fmaxf(c, 1.0f);
        out[n_graphs + g * 32 + k] = rep;
        float t = rep * Wh[k];
        #pragma unroll
        for (int d = 16; d > 0; d >>= 1) t += __shfl_down(t, d, 32);
        if (k == 0) out[g] = t + bh[0];
    }
}

// ---------------- launch ----------------

extern "C" void kernel_launch(void* const* d_in, const int* in_sizes, int n_in,
                              void* d_out, int out_size, void* d_ws, size_t ws_size,
                              hipStream_t stream) {
    const float* x   = (const float*)d_in[0];
    const float* p   = (const float*)d_in[1];
    const float* ea  = (const float*)d_in[2];
    const float* Wx0 = (const float*)d_in[3];
    const float* Wx1 = (const float*)d_in[4];
    const float* Wx2 = (const float*)d_in[5];
    const float* Wp0 = (const float*)d_in[6];
    const float* Wp1 = (const float*)d_in[7];
    const float* Wp2 = (const float*)d_in[8];
    const float* We0 = (const float*)d_in[9];
    const float* We1 = (const float*)d_in[10];
    const float* We2 = (const float*)d_in[11];
    const float* b0  = (const float*)d_in[12];
    const float* b1  = (const float*)d_in[13];
    const float* b2  = (const float*)d_in[14];
    const float* Wh  = (const float*)d_in[15];
    const float* bh  = (const float*)d_in[16];
    const int* edge_index = (const int*)d_in[17];
    const int* batch      = (const int*)d_in[18];

    const int N = in_sizes[0] / 5;
    const int E = in_sizes[17] / 2;
    const int G = out_size / 33;

    const int NP = (N + 1023) & ~1023;
    const int NTILE = NP / 1024;

    const int* srcp = edge_index;
    const int* dstp = edge_index + E;

    char* w = (char*)d_ws;
    auto alloc = [&](size_t bytes) -> void* {
        void* r = (void*)w;
        w += (bytes + 255) & ~(size_t)255;
        return r;
    };
    int*   cnt    = (int*)alloc((size_t)NP * 4);
    int*   off    = (int*)alloc((size_t)(N + 1) * 4);
    int*   cur    = (int*)alloc((size_t)N * 4);
    int*   part   = (int*)alloc((size_t)NTILE * 4);
    uint2* packed = (uint2*)alloc((size_t)E * 8);
    float* M      = (float*)alloc((size_t)N * K_DIM * 4);
    float* hA     = (float*)alloc((size_t)N * K_DIM * 4);
    float* hB     = (float*)alloc((size_t)N * K_DIM * 4);

    // CSR by dst
    (void)hipMemsetAsync(cnt, 0, (size_t)NP * 4, stream);
    k_hist<<<2048, 256, 0, stream>>>(dstp, cnt, E);
    k_scan_part<<<NTILE, 256, 0, stream>>>(cnt, part);
    k_scan_top<<<1, 128, 0, stream>>>(part, NTILE, off, N, E);
    k_scan_apply<<<NTILE, 256, 0, stream>>>(cnt, part, off, cur, N);

    // sliced scatter: each pass's write window (~3.2MB) is L2-resident
    const int NSLICE = 8;
    const int per = (N + NSLICE - 1) / NSLICE;
    for (int s = 0; s < NSLICE; ++s) {
        int lo = s * per;
        int hi = (lo + per < N) ? lo + per : N;
        k_scatter_slice<<<2048, 256, 0, stream>>>(srcp, dstp, ea, cur, packed, E, lo, hi);
    }

    const int NB = (N + 3) / 4;   // 4 wave64-nodes per 256-thread block

    // layer 0
    k_node_gemm5<<<(N + 7) / 8, 256, 0, stream>>>(x, p, Wx0, Wp0, M, N);
    k_edge_msg<<<NB, 256, 0, stream>>>(M, p, off, packed, Wp0, We0, b0, hA, N);
    k_prop_gemm<1><<<NB, 256, 0, stream>>>(hA, off, packed, p, Wx1, Wp1, M, N);
    // layer 1
    k_edge_msg<<<NB, 256, 0, stream>>>(M, p, off, packed, Wp1, We1, b1, hA, N);
    k_prop_gemm<1><<<NB, 256, 0, stream>>>(hA, off, packed, p, Wx2, Wp2, M, N);
    // layer 2
    k_edge_msg<<<NB, 256, 0, stream>>>(M, p, off, packed, Wp2, We2, b2, hA, N);
    k_prop_gemm<0><<<NB, 256, 0, stream>>>(hA, off, packed, p, nullptr, nullptr, hB, N);

    // pool + head
    k_pool<<<G, 256, 0, stream>>>(hB, batch, Wh, bh, (float*)d_out, N, G);
}

// Round 5
// 789.018 us; speedup vs baseline: 1.8183x; 1.8183x over previous
//
#include <hip/hip_runtime.h>
#include <hip/hip_fp16.h>

#define K_DIM 32

__device__ __forceinline__ float tanh_fast(float x) {
    // tanh(x) = 1 - 2/(e^{2x}+1); exact at saturation, ~1e-7 abs error
    float e = __expf(2.0f * x);
    return 1.0f - 2.0f / (e + 1.0f);
}

// ---------------- CSR build ----------------

__global__ void k_hist(const int* __restrict__ dst, int* __restrict__ cnt, int n) {
    for (int e = blockIdx.x * blockDim.x + threadIdx.x; e < n; e += gridDim.x * blockDim.x)
        atomicAdd(&cnt[dst[e]], 1);
}

__global__ void k_scan_part(const int* __restrict__ cnt, int* __restrict__ part) {
    __shared__ int sm[256];
    int t = threadIdx.x;
    int g = blockIdx.x * 1024 + t * 4;
    const int4 v = *(const int4*)(cnt + g);
    sm[t] = v.x + v.y + v.z + v.w;
    __syncthreads();
    #pragma unroll
    for (int d = 128; d > 0; d >>= 1) {
        if (t < d) sm[t] += sm[t + d];
        __syncthreads();
    }
    if (t == 0) part[blockIdx.x] = sm[0];
}

__global__ void k_scan_top(int* __restrict__ part, int nblk,
                           int* __restrict__ off, int n, int total) {
    __shared__ int sm[128];
    int t = threadIdx.x;
    sm[t] = (t < nblk) ? part[t] : 0;
    __syncthreads();
    #pragma unroll
    for (int d = 1; d < 128; d <<= 1) {
        int v = (t >= d) ? sm[t - d] : 0;
        __syncthreads();
        sm[t] += v;
        __syncthreads();
    }
    if (t < nblk) part[t] = sm[t];
    if (t == 0) off[n] = total;
}

__global__ void k_scan_apply(const int* __restrict__ cnt, const int* __restrict__ part,
                             int* __restrict__ off, int* __restrict__ cur, int n) {
    __shared__ int sm[256];
    int t = threadIdx.x;
    int g = blockIdx.x * 1024 + t * 4;
    const int4 v = *(const int4*)(cnt + g);
    int s0 = v.x, s1 = s0 + v.y, s2 = s1 + v.z, s3 = s2 + v.w;
    sm[t] = s3;
    __syncthreads();
    #pragma unroll
    for (int d = 1; d < 256; d <<= 1) {
        int tv = (t >= d) ? sm[t - d] : 0;
        __syncthreads();
        sm[t] += tv;
        __syncthreads();
    }
    int carry = blockIdx.x ? part[blockIdx.x - 1] : 0;
    int excl = (t ? sm[t - 1] : 0) + carry;
    if (g + 3 < n) {
        int4 o = make_int4(excl, excl + s0, excl + s1, excl + s2);
        *(int4*)(off + g) = o;
        *(int4*)(cur + g) = o;
    } else {
        int pre[4] = {0, s0, s1, s2};
        #pragma unroll
        for (int j = 0; j < 4; ++j)
            if (g + j < n) { off[g + j] = excl + pre[j]; cur[g + j] = excl + pre[j]; }
    }
}

// scatter restricted to dst in [lo,hi): write window ~3.2MB -> L2-resident
__global__ void k_scatter_slice(const int* __restrict__ src, const int* __restrict__ dst,
                                const float* __restrict__ ea, int* __restrict__ cur,
                                uint2* __restrict__ packed, int n, int lo, int hi) {
    for (int e = blockIdx.x * blockDim.x + threadIdx.x; e < n; e += gridDim.x * blockDim.x) {
        int d = dst[e];
        if (d >= lo && d < hi) {
            int pos = atomicAdd(&cur[d], 1);
            packed[pos] = make_uint2((unsigned)src[e], __float_as_uint(ea[e]));
        }
    }
}

// ---------------- per-layer kernels ----------------

// layer-0: M = x@Wx0 + p@Wp0, fp16 output
__global__ void k_node_gemm5(const float* __restrict__ h, const float* __restrict__ p,
                             const float* __restrict__ Wx, const float* __restrict__ Wp,
                             __half* __restrict__ Mh, int n_nodes) {
    __shared__ float sWx[5 * 32];
    __shared__ float sWp[96];
    for (int i = threadIdx.x; i < 5 * 32; i += blockDim.x) sWx[i] = Wx[i];
    if (threadIdx.x < 96) sWp[threadIdx.x] = Wp[threadIdx.x];
    __syncthreads();
    const int k = threadIdx.x & 31;
    int n = blockIdx.x * (blockDim.x >> 5) + (threadIdx.x >> 5);
    if (n >= n_nodes) return;
    float hv = (k < 5) ? h[n * 5 + k] : 0.0f;
    float pv = (k < 3) ? p[n * 3 + k] : 0.0f;
    float acc = 0.0f;
    #pragma unroll
    for (int j = 0; j < 5; ++j) acc = fmaf(__shfl(hv, j, 32), sWx[j * 32 + k], acc);
    #pragma unroll
    for (int j = 0; j < 3; ++j) acc = fmaf(__shfl(pv, j, 32), sWp[j * 32 + k], acc);
    Mh[n * 32 + k] = __float2half(acc);
}

// sim[n][k] = sum_{e: dst==n} tanh(M[src_e][k] + cnst_n[k] + ea_e*We[k])
// 32-lane group per node; 4 independent fp16 row-gathers in flight.
__global__ void k_edge_msg(const __half* __restrict__ Mh, const float* __restrict__ p,
                           const int* __restrict__ off, const uint2* __restrict__ packed,
                           const float* __restrict__ Wp, const float* __restrict__ We,
                           const float* __restrict__ b,
                           __half* __restrict__ simh, int n_nodes) {
    const int k = threadIdx.x & 31;
    int n = blockIdx.x * (blockDim.x >> 5) + (threadIdx.x >> 5);
    if (n >= n_nodes) return;

    float pn = (k < 3) ? p[n * 3 + k] : 0.0f;
    float cnst = b[k] - (__shfl(pn, 0, 32) * Wp[k] + __shfl(pn, 1, 32) * Wp[32 + k]
                         + __shfl(pn, 2, 32) * Wp[64 + k]);
    float we = We[k];
    float acc = 0.0f;

    int e0 = off[n], e1 = off[n + 1];
    for (int base = e0; base < e1; base += 32) {
        int m = min(32, e1 - base);
        uint2 pk = make_uint2(0u, 0u);            // lanes >= m broadcast s=0 (safe row)
        if (k < m) pk = packed[base + k];
        for (int j = 0; j < m; j += 4) {
            int s0 = __shfl((int)pk.x, j, 32);
            int s1 = __shfl((int)pk.x, j + 1, 32);
            int s2 = __shfl((int)pk.x, j + 2, 32);
            int s3 = __shfl((int)pk.x, j + 3, 32);
            float a0 = __uint_as_float((unsigned)__shfl((int)pk.y, j, 32));
            float a1 = __uint_as_float((unsigned)__shfl((int)pk.y, j + 1, 32));
            float a2 = __uint_as_float((unsigned)__shfl((int)pk.y, j + 2, 32));
            float a3 = __uint_as_float((unsigned)__shfl((int)pk.y, j + 3, 32));
            float m0 = __half2float(Mh[s0 * 32 + k]);   // 4 independent gathers
            float m1 = __half2float(Mh[s1 * 32 + k]);
            float m2 = __half2float(Mh[s2 * 32 + k]);
            float m3 = __half2float(Mh[s3 * 32 + k]);
            float t0 = tanh_fast(fmaf(a0, we, cnst) + m0);
            float t1 = tanh_fast(fmaf(a1, we, cnst) + m1);
            float t2 = tanh_fast(fmaf(a2, we, cnst) + m2);
            float t3 = tanh_fast(fmaf(a3, we, cnst) + m3);
            acc += t0;                                   // j < m always
            if (j + 1 < m) acc += t1;
            if (j + 2 < m) acc += t2;
            if (j + 3 < m) acc += t3;
        }
    }
    simh[n * 32 + k] = __float2half(acc);
}

// h_next[n] = sum over in-edges of sim[src]; optionally fused next-layer GEMM
template <int FUSE>
__global__ void k_prop_gemm(const __half* __restrict__ simh, const int* __restrict__ off,
                            const uint2* __restrict__ packed, const float* __restrict__ p,
                            const float* __restrict__ Wx, const float* __restrict__ Wp,
                            __half* __restrict__ outMh, float* __restrict__ outF,
                            int n_nodes) {
    __shared__ float sWx[1024];
    if (FUSE) {
        for (int i = threadIdx.x; i < 1024; i += blockDim.x) sWx[i] = Wx[i];
        __syncthreads();
    }
    const int k = threadIdx.x & 31;
    int n = blockIdx.x * (blockDim.x >> 5) + (threadIdx.x >> 5);
    if (n >= n_nodes) return;

    float acc = 0.0f;
    int e0 = off[n], e1 = off[n + 1];
    for (int base = e0; base < e1; base += 32) {
        int m = min(32, e1 - base);
        unsigned sv = 0u;
        if (k < m) sv = packed[base + k].x;
        for (int j = 0; j < m; j += 4) {
            int s0 = __shfl((int)sv, j, 32);
            int s1 = __shfl((int)sv, j + 1, 32);
            int s2 = __shfl((int)sv, j + 2, 32);
            int s3 = __shfl((int)sv, j + 3, 32);
            float v0 = __half2float(simh[s0 * 32 + k]);
            float v1 = __half2float(simh[s1 * 32 + k]);
            float v2 = __half2float(simh[s2 * 32 + k]);
            float v3 = __half2float(simh[s3 * 32 + k]);
            acc += v0;
            if (j + 1 < m) acc += v1;
            if (j + 2 < m) acc += v2;
            if (j + 3 < m) acc += v3;
        }
    }

    if (!FUSE) { outF[n * 32 + k] = acc; return; }
    float mm = 0.0f;
    #pragma unroll
    for (int j = 0; j < 32; ++j) mm = fmaf(__shfl(acc, j, 32), sWx[j * 32 + k], mm);
    float pv = (k < 3) ? p[n * 3 + k] : 0.0f;
    mm = fmaf(__shfl(pv, 0, 32), Wp[k], mm);
    mm = fmaf(__shfl(pv, 1, 32), Wp[32 + k], mm);
    mm = fmaf(__shfl(pv, 2, 32), Wp[64 + k], mm);
    outMh[n * 32 + k] = __float2half(mm);
}

// ---------------- pooling + head ----------------

__global__ void k_pool(const float* __restrict__ h, const int* __restrict__ batch,
                       const float* __restrict__ Wh, const float* __restrict__ bh,
                       float* __restrict__ out, int n_nodes, int n_graphs) {
    __shared__ int sLo, sHi;
    __shared__ float red[256];
    int g = blockIdx.x;
    if (threadIdx.x == 0) {
        int lo = 0, hi = n_nodes;
        while (lo < hi) { int m = (lo + hi) >> 1; if (batch[m] < g) lo = m + 1; else hi = m; }
        sLo = lo;
        lo = 0; hi = n_nodes; int g1 = g + 1;
        while (lo < hi) { int m = (lo + hi) >> 1; if (batch[m] < g1) lo = m + 1; else hi = m; }
        sHi = lo;
    }
    __syncthreads();
    int lo = sLo, hi = sHi;
    int k = threadIdx.x & 31, r = threadIdx.x >> 5;
    float acc = 0.0f;
    for (int n = lo + r; n < hi; n += 8) acc += h[n * 32 + k];
    red[threadIdx.x] = acc;
    __syncthreads();
    if (threadIdx.x < 32) {
        float s = 0.0f;
        #pragma unroll
        for (int r2 = 0; r2 < 8; ++r2) s += red[r2 * 32 + k];
        float c = (float)(hi - lo);
        float rep = s / fmaxf(c, 1.0f);
        out[n_graphs + g * 32 + k] = rep;
        float t = rep * Wh[k];
        #pragma unroll
        for (int d = 16; d > 0; d >>= 1) t += __shfl_down(t, d, 32);
        if (k == 0) out[g] = t + bh[0];
    }
}

// ---------------- launch ----------------

extern "C" void kernel_launch(void* const* d_in, const int* in_sizes, int n_in,
                              void* d_out, int out_size, void* d_ws, size_t ws_size,
                              hipStream_t stream) {
    const float* x   = (const float*)d_in[0];
    const float* p   = (const float*)d_in[1];
    const float* ea  = (const float*)d_in[2];
    const float* Wx0 = (const float*)d_in[3];
    const float* Wx1 = (const float*)d_in[4];
    const float* Wx2 = (const float*)d_in[5];
    const float* Wp0 = (const float*)d_in[6];
    const float* Wp1 = (const float*)d_in[7];
    const float* Wp2 = (const float*)d_in[8];
    const float* We0 = (const float*)d_in[9];
    const float* We1 = (const float*)d_in[10];
    const float* We2 = (const float*)d_in[11];
    const float* b0  = (const float*)d_in[12];
    const float* b1  = (const float*)d_in[13];
    const float* b2  = (const float*)d_in[14];
    const float* Wh  = (const float*)d_in[15];
    const float* bh  = (const float*)d_in[16];
    const int* edge_index = (const int*)d_in[17];
    const int* batch      = (const int*)d_in[18];

    const int N = in_sizes[0] / 5;
    const int E = in_sizes[17] / 2;
    const int G = out_size / 33;

    const int NP = (N + 1023) & ~1023;
    const int NTILE = NP / 1024;

    const int* srcp = edge_index;
    const int* dstp = edge_index + E;

    char* w = (char*)d_ws;
    auto alloc = [&](size_t bytes) -> void* {
        void* r = (void*)w;
        w += (bytes + 255) & ~(size_t)255;
        return r;
    };
    int*    cnt    = (int*)alloc((size_t)NP * 4);
    int*    off    = (int*)alloc((size_t)(N + 1) * 4);
    int*    cur    = (int*)alloc((size_t)N * 4);
    int*    part   = (int*)alloc((size_t)NTILE * 4);
    uint2*  packed = (uint2*)alloc((size_t)E * 8);
    __half* Mh     = (__half*)alloc((size_t)N * K_DIM * 2);
    __half* simh   = (__half*)alloc((size_t)N * K_DIM * 2);
    float*  hB     = (float*)alloc((size_t)N * K_DIM * 4);

    // CSR by dst
    (void)hipMemsetAsync(cnt, 0, (size_t)NP * 4, stream);
    k_hist<<<2048, 256, 0, stream>>>(dstp, cnt, E);
    k_scan_part<<<NTILE, 256, 0, stream>>>(cnt, part);
    k_scan_top<<<1, 128, 0, stream>>>(part, NTILE, off, N, E);
    k_scan_apply<<<NTILE, 256, 0, stream>>>(cnt, part, off, cur, N);

    // sliced scatter: each pass's write window (~3.2MB) is L2-resident
    const int NSLICE = 8;
    const int per = (N + NSLICE - 1) / NSLICE;
    for (int s = 0; s < NSLICE; ++s) {
        int lo = s * per;
        int hi = (lo + per < N) ? lo + per : N;
        k_scatter_slice<<<2048, 256, 0, stream>>>(srcp, dstp, ea, cur, packed, E, lo, hi);
    }

    const int NB = (N + 7) / 8;   // 8 node-groups (32 lanes) per 256-thread block

    // layer 0
    k_node_gemm5<<<NB, 256, 0, stream>>>(x, p, Wx0, Wp0, Mh, N);
    k_edge_msg<<<NB, 256, 0, stream>>>(Mh, p, off, packed, Wp0, We0, b0, simh, N);
    k_prop_gemm<1><<<NB, 256, 0, stream>>>(simh, off, packed, p, Wx1, Wp1, Mh, nullptr, N);
    // layer 1
    k_edge_msg<<<NB, 256, 0, stream>>>(Mh, p, off, packed, Wp1, We1, b1, simh, N);
    k_prop_gemm<1><<<NB, 256, 0, stream>>>(simh, off, packed, p, Wx2, Wp2, Mh, nullptr, N);
    // layer 2
    k_edge_msg<<<NB, 256, 0, stream>>>(Mh, p, off, packed, Wp2, We2, b2, simh, N);
    k_prop_gemm<0><<<NB, 256, 0, stream>>>(simh, off, packed, p, nullptr, nullptr, nullptr, hB, N);

    // pool + head
    k_pool<<<G, 256, 0, stream>>>(hB, batch, Wh, bh, (float*)d_out, N, G);
}